// Round 4
// baseline (95022.113 us; speedup 1.0000x reference)
//
#include <hip/hip_runtime.h>
#include <hip/hip_bf16.h>

using bf16 = __hip_bfloat16;
typedef __attribute__((ext_vector_type(8))) short short8;
typedef __attribute__((ext_vector_type(4))) float floatx4;

static constexpr int B_ = 256;   // batch
static constexpr int T_ = 128;   // time steps
static constexpr int GRID = 512; // 2 blocks/CU, cooperative

__device__ __forceinline__ float bf2f(bf16 v) { return __bfloat162float(v); }
__device__ __forceinline__ bf16  f2bf(float v) { return __float2bfloat16(v); }

enum { MG = 0, MC = 1, MD = 2 };

struct Params {
    const bf16* emb;        // [T][B][32]
    const int*  lens;
    const bf16* kgT[3];     // [2*out][Kt]  (transposed)
    const bf16* kcT[3];     // [out][Kt]
    const float* gb[3];
    const float* cb[3];
    float* hf[3];           // fp32 running h
    bf16*  hb[3];           // bf16 h
    bf16*  rh[3];           // bf16 r*h
    float* zb[3];           // fp32 z
    const bf16* dwT;        // [512][3584]
    const float* db;
    float* y;               // [256][512] fp32
    unsigned* ctr;          // 768 one-shot phase counters
};

// one-sided grid barrier: wb-fence, count, spin, inv-fence
__device__ __forceinline__ void phase_barrier(unsigned* c)
{
    __syncthreads();
    __threadfence();                        // write-back our stores (L2 -> LLC)
    if (threadIdx.x == 0) {
        atomicAdd(c, 1u);
        while (__hip_atomic_load(c, __ATOMIC_RELAXED, __HIP_MEMORY_SCOPE_AGENT) < (unsigned)GRID)
            __builtin_amdgcn_s_sleep(1);
    }
    __syncthreads();
    __threadfence();                        // invalidate so we see others' stores
}

// ---- fp32 [K][N] -> bf16 [N][K] tiled transpose ----
__global__ __launch_bounds__(256) void tpose_k(const float* __restrict__ src,
                                               bf16* __restrict__ dst,
                                               int K, int N)
{
    __shared__ float tile[32][33];
    const int kb = blockIdx.x * 32, nb = blockIdx.y * 32;
    const int tx = threadIdx.x & 31, ty = threadIdx.x >> 5;
    for (int i = ty; i < 32; i += 8)
        tile[i][tx] = src[(size_t)(kb + i) * N + nb + tx];
    __syncthreads();
    for (int i = ty; i < 32; i += 8)
        dst[(size_t)(nb + i) * K + kb + tx] = f2bf(tile[tx][i]);
}

// ---- emb_all[t][b][0:32] = bf16(emb_table[seq[b][t]]) ----
__global__ __launch_bounds__(256) void embed_k(const int* __restrict__ seq,
                                               const float* __restrict__ tab,
                                               bf16* __restrict__ emb_all)
{
    int c = blockIdx.x * 256 + threadIdx.x;
    int t = c >> 10;
    int r = c & 1023;
    int b = r >> 2, i = r & 3;
    int tok = seq[b * T_ + t];
    const float* s = tab + (size_t)tok * 32 + i * 8;
    bf16 tmp[8];
#pragma unroll
    for (int j = 0; j < 8; ++j) tmp[j] = f2bf(s[j]);
    *(uint4*)(emb_all + ((size_t)t * B_ + b) * 32 + i * 8) = *(uint4*)tmp;
}

// All tiles this block owns for one GEMM phase.
// A = [s0|s1|s2] row-major bf16 segments (ends e0<=e1<=e2, multiples of 32).
// BT = bf16 [N][e2]. Block tile 64x64, 4 waves of 32x32 (16x16x32 mfma),
// depth-2 register prefetch of global loads.
__device__ void gemm_tiles(int mode,
    const bf16* s0, int ld0, int e0,
    const bf16* s1, int ld1, int e1,
    const bf16* s2, int ld2, int e2,
    const bf16* __restrict__ BT,
    const float* __restrict__ bias, int N, int out,
    float* hf, bf16* hb, bf16* rh, float* zb,
    const int* lens, int t, float* y,
    bf16* As, bf16* Bs)
{
    const int tid  = threadIdx.x;
    const int bid  = blockIdx.x;
    const int Nt   = N >> 6;
    const int cn   = (Nt + 7) >> 3;          // n-tiles per XCD group
    const int xcd  = bid & 7, jj = bid >> 3; // assume bid%8 ~ XCD (perf-only)
    const int lane = tid & 63, wv = tid >> 6;
    const int wm   = (wv >> 1) * 32, wn = (wv & 1) * 32;
    const int quad = lane >> 4, l16 = lane & 15;
    const int srow = tid >> 2, skc = (tid & 3) * 8;

    for (int v = jj; v < 4 * cn; v += 64) {
        const int ni = xcd * cn + (v >> 2);
        if (ni >= Nt) break;
        const int bm = (v & 3) * 64;
        const int bn = ni * 64;

        floatx4 acc00 = {0,0,0,0}, acc01 = {0,0,0,0};
        floatx4 acc10 = {0,0,0,0}, acc11 = {0,0,0,0};

        auto aload = [&](int k0) -> uint4 {
            const bf16* sp; int kb;
            if (k0 < e0)      { sp = s0 + (size_t)(bm + srow) * ld0; kb = k0; }
            else if (k0 < e1) { sp = s1 + (size_t)(bm + srow) * ld1; kb = k0 - e0; }
            else              { sp = s2 + (size_t)(bm + srow) * ld2; kb = k0 - e1; }
            return *(const uint4*)(sp + kb + skc);
        };
        const bf16* btrow = BT + (size_t)(bn + srow) * e2 + skc;

        // depth-2 prefetch pipeline (all Kt >= 64 here)
        uint4 a0 = aload(0),  b0 = *(const uint4*)(btrow);
        uint4 a1 = aload(32), b1 = *(const uint4*)(btrow + 32);

        for (int k0 = 0; k0 < e2; k0 += 32) {
            *(uint4*)&As[srow * 40 + skc] = a0;
            *(uint4*)&Bs[srow * 40 + skc] = b0;
            __syncthreads();

            uint4 an, bn2;
            const bool more = (k0 + 64) < e2;
            if (more) { an = aload(k0 + 64); bn2 = *(const uint4*)(btrow + k0 + 64); }

            short8 af0 = *(const short8*)&As[(wm + l16) * 40 + quad * 8];
            short8 af1 = *(const short8*)&As[(wm + 16 + l16) * 40 + quad * 8];
            short8 bw0 = *(const short8*)&Bs[(wn + l16) * 40 + quad * 8];
            short8 bw1 = *(const short8*)&Bs[(wn + 16 + l16) * 40 + quad * 8];

            acc00 = __builtin_amdgcn_mfma_f32_16x16x32_bf16(af0, bw0, acc00, 0, 0, 0);
            acc01 = __builtin_amdgcn_mfma_f32_16x16x32_bf16(af0, bw1, acc01, 0, 0, 0);
            acc10 = __builtin_amdgcn_mfma_f32_16x16x32_bf16(af1, bw0, acc10, 0, 0, 0);
            acc11 = __builtin_amdgcn_mfma_f32_16x16x32_bf16(af1, bw1, acc11, 0, 0, 0);

            __syncthreads();
            a0 = a1; b0 = b1;
            if (more) { a1 = an; b1 = bn2; }
        }

        // ---- epilogue (R2-verified 2x2 layout) ----
#pragma unroll
        for (int tm = 0; tm < 2; ++tm)
#pragma unroll
            for (int tn = 0; tn < 2; ++tn) {
                floatx4 a;
                if (tm == 0) a = (tn == 0) ? acc00 : acc01;
                else         a = (tn == 0) ? acc10 : acc11;
                const int col = bn + wn + tn * 16 + l16;
#pragma unroll
                for (int r = 0; r < 4; ++r) {
                    const int row = bm + wm + tm * 16 + quad * 4 + r;
                    float vv = a[r] + bias[col];
                    if (mode == MG) {
                        float s = 1.f / (1.f + __expf(-vv));
                        if (col < out) {
                            size_t idx = (size_t)row * out + col;
                            rh[idx] = f2bf(s * hf[idx]);
                        } else {
                            zb[(size_t)row * out + (col - out)] = s;
                        }
                    } else if (mode == MC) {
                        float c = tanhf(vv);
                        size_t idx = (size_t)row * out + col;
                        float zv = zb[idx], ho = hf[idx];
                        float hn = (t < lens[row]) ? (zv * ho + (1.f - zv) * c) : ho;
                        hf[idx] = hn;
                        hb[idx] = f2bf(hn);
                    } else {
                        y[(size_t)row * 512 + col] = tanhf(vv);
                    }
                }
            }
    }
}

__global__ __launch_bounds__(256, 2) void gru_k(Params p)
{
    __shared__ __align__(16) bf16 As[64 * 40];
    __shared__ __align__(16) bf16 Bs[64 * 40];
    const int outs[3] = {512, 1024, 2048};
    int pc = 0;

    for (int t = 0; t < T_; ++t) {
        const bf16* x = p.emb + (size_t)t * B_ * 32;
        int ldx = 32, kx = 32;
        for (int l = 0; l < 3; ++l) {
            const int out = outs[l];
            const int Kt = kx + out;
            gemm_tiles(MG, x, ldx, kx, p.hb[l], out, Kt, nullptr, 0, Kt,
                       p.kgT[l], p.gb[l], 2 * out, out,
                       p.hf[l], nullptr, p.rh[l], p.zb[l], nullptr, 0, nullptr, As, Bs);
            phase_barrier(&p.ctr[pc++]);
            gemm_tiles(MC, x, ldx, kx, p.rh[l], out, Kt, nullptr, 0, Kt,
                       p.kcT[l], p.cb[l], out, out,
                       p.hf[l], p.hb[l], nullptr, p.zb[l], p.lens, t, nullptr, As, Bs);
            phase_barrier(&p.ctr[pc++]);
            x = p.hb[l]; ldx = out; kx = out;
        }
    }
    gemm_tiles(MD, p.hb[0], 512, 512, p.hb[1], 1024, 1536, p.hb[2], 2048, 3584,
               p.dwT, p.db, 512, 512,
               nullptr, nullptr, nullptr, nullptr, nullptr, 0, p.y, As, Bs);
}

extern "C" void kernel_launch(void* const* d_in, const int* in_sizes, int n_in,
                              void* d_out, int out_size, void* d_ws, size_t ws_size,
                              hipStream_t stream)
{
    const int*   seq  = (const int*)d_in[0];
    const int*   lens = (const int*)d_in[1];
    const float* tab  = (const float*)d_in[2];
    const float* gkF[3] = {(const float*)d_in[3], (const float*)d_in[7], (const float*)d_in[11]};
    const float* gbF[3] = {(const float*)d_in[4], (const float*)d_in[8], (const float*)d_in[12]};
    const float* ckF[3] = {(const float*)d_in[5], (const float*)d_in[9], (const float*)d_in[13]};
    const float* cbF[3] = {(const float*)d_in[6], (const float*)d_in[10], (const float*)d_in[14]};
    const float* dwF = (const float*)d_in[15];
    const float* dbF = (const float*)d_in[16];

    const int outs[3] = {512, 1024, 2048};
    const int ins[3]  = {32, 512, 1024};

    char* w = (char*)d_ws;
    auto alloc = [&](size_t bytes) -> void* {
        void* pp = (void*)w;
        w += (bytes + 255) & ~(size_t)255;
        return pp;
    };

    Params p;
    p.lens = lens;
    p.db   = dbF;
    p.y    = (float*)d_out;

    bf16* kgT[3]; bf16* kcT[3];
    for (int l = 0; l < 3; ++l) {
        const int Kt = ins[l] + outs[l];
        kgT[l] = (bf16*)alloc((size_t)2 * outs[l] * Kt * sizeof(bf16));
        kcT[l] = (bf16*)alloc((size_t)outs[l] * Kt * sizeof(bf16));
        p.kgT[l] = kgT[l];
        p.kcT[l] = kcT[l];
        p.gb[l] = gbF[l];
        p.cb[l] = cbF[l];
    }
    bf16* dwT = (bf16*)alloc((size_t)512 * 3584 * sizeof(bf16));
    p.dwT = dwT;

    bf16* emb_all = (bf16*)alloc((size_t)T_ * B_ * 32 * sizeof(bf16));
    p.emb = emb_all;

    for (int l = 0; l < 3; ++l) {
        p.hf[l] = (float*)alloc((size_t)B_ * outs[l] * sizeof(float));
        p.hb[l] = (bf16*)alloc((size_t)B_ * outs[l] * sizeof(bf16));
        p.rh[l] = (bf16*)alloc((size_t)B_ * outs[l] * sizeof(bf16));
        p.zb[l] = (float*)alloc((size_t)B_ * outs[l] * sizeof(float));
    }
    unsigned* ctr = (unsigned*)alloc(1024 * sizeof(unsigned));
    p.ctr = ctr;

    // weight transposes (fp32 -> bf16 [N][K])
    for (int l = 0; l < 3; ++l) {
        const int Kt = ins[l] + outs[l];
        tpose_k<<<dim3(Kt / 32, 2 * outs[l] / 32), 256, 0, stream>>>(gkF[l], kgT[l], Kt, 2 * outs[l]);
        tpose_k<<<dim3(Kt / 32, outs[l] / 32), 256, 0, stream>>>(ckF[l], kcT[l], Kt, outs[l]);
    }
    tpose_k<<<dim3(3584 / 32, 512 / 32), 256, 0, stream>>>(dwF, dwT, 3584, 512);

    // zero h state + phase counters
    for (int l = 0; l < 3; ++l) {
        hipMemsetAsync(p.hf[l], 0, (size_t)B_ * outs[l] * sizeof(float), stream);
        hipMemsetAsync(p.hb[l], 0, (size_t)B_ * outs[l] * sizeof(bf16), stream);
    }
    hipMemsetAsync(ctr, 0, 1024 * sizeof(unsigned), stream);

    embed_k<<<T_ * B_ * 4 / 256, 256, 0, stream>>>(seq, tab, emb_all);

    void* args[] = {&p};
    hipLaunchCooperativeKernel(reinterpret_cast<void*>(gru_k),
                               dim3(GRID), dim3(256), args, 0, stream);
}

// Round 6
// 48412.906 us; speedup vs baseline: 1.9627x; 1.9627x over previous
//
#include <hip/hip_runtime.h>
#include <hip/hip_bf16.h>

using bf16 = __hip_bfloat16;
typedef __attribute__((ext_vector_type(8))) short short8;
typedef __attribute__((ext_vector_type(4))) float floatx4;

static constexpr int B_ = 256;   // batch
static constexpr int T_ = 128;   // time steps
static constexpr int GRID = 512; // 2 blocks/CU, cooperative

__device__ __forceinline__ bf16 f2bf(float v) { return __float2bfloat16(v); }

enum { MG = 0, MC = 1, MD = 2 };

struct Params {
    const bf16* emb;          // [T][B][32]
    const int*  lens;
    const bf16* kgT[3];       // [2*out][Kt] transposed bf16
    const bf16* kcT[3];       // [out][Kt]
    const float* gb[3];
    const float* cb[3];
    float* hf[3];             // fp32 running h
    bf16*  hb[3][2];          // bf16 h, double-buffered by t parity
    bf16*  rh[3];             // bf16 r*h
    float* zb[3];             // fp32 z
    const bf16* dwT;          // [512][3584]
    const float* db;
    float* y;                 // [256][512] fp32
    unsigned* ctr;            // one-shot counters, stride 32 uints per barrier
};

// R4-proven one-shot grid barrier (device-scope atomics + fences)
__device__ __forceinline__ void phase_barrier(unsigned* c)
{
    __syncthreads();
    __threadfence();
    if (threadIdx.x == 0) {
        atomicAdd(c, 1u);
        while (__hip_atomic_load(c, __ATOMIC_RELAXED, __HIP_MEMORY_SCOPE_AGENT) < (unsigned)GRID)
            __builtin_amdgcn_s_sleep(1);
    }
    __syncthreads();
    __threadfence();
}

// ---- fp32 [K][N] -> bf16 [N][K] tiled transpose ----
__global__ __launch_bounds__(256) void tpose_k(const float* __restrict__ src,
                                               bf16* __restrict__ dst,
                                               int K, int N)
{
    __shared__ float tile[32][33];
    const int kb = blockIdx.x * 32, nb = blockIdx.y * 32;
    const int tx = threadIdx.x & 31, ty = threadIdx.x >> 5;
    for (int i = ty; i < 32; i += 8)
        tile[i][tx] = src[(size_t)(kb + i) * N + nb + tx];
    __syncthreads();
    for (int i = ty; i < 32; i += 8)
        dst[(size_t)(nb + i) * K + kb + tx] = f2bf(tile[tx][i]);
}

// ---- emb_all[t][b][0:32] = bf16(emb_table[seq[b][t]]) ----
__global__ __launch_bounds__(256) void embed_k(const int* __restrict__ seq,
                                               const float* __restrict__ tab,
                                               bf16* __restrict__ emb_all)
{
    int c = blockIdx.x * 256 + threadIdx.x;
    int t = c >> 10;
    int r = c & 1023;
    int b = r >> 2, i = r & 3;
    int tok = seq[b * T_ + t];
    const float* s = tab + (size_t)tok * 32 + i * 8;
    bf16 tmp[8];
#pragma unroll
    for (int j = 0; j < 8; ++j) tmp[j] = f2bf(s[j]);
    *(uint4*)(emb_all + ((size_t)t * B_ + b) * 32 + i * 8) = *(uint4*)tmp;
}

// One 64x64 tile, no LDS. A = [s0|s1|s2] row-major bf16 (compile-time segment
// ends E0<=E1<=E2, multiples of 32). BT = bf16 [N][E2]. 4 waves of 32x32 via
// 16x16x32 mfma. Depth-4 rotating register pipeline bounds VGPR use while
// keeping 16 loads/lane in flight.
template <int E0, int E1, int E2, int MODE>
__device__ void phase_gemm(
    const bf16* __restrict__ s0, int ld0,
    const bf16* __restrict__ s1, int ld1,
    const bf16* __restrict__ s2, int ld2,
    const bf16* __restrict__ BT,
    const float* __restrict__ bias, int out,
    float* __restrict__ hf, bf16* __restrict__ hbo,
    bf16* __restrict__ rh, float* __restrict__ zb,
    const int* __restrict__ lens, int t, float* __restrict__ y,
    int bm, int bn)
{
    const int tid  = threadIdx.x;
    const int lane = tid & 63, wv = tid >> 6;
    const int wm   = (wv >> 1) * 32, wn = (wv & 1) * 32;
    const int quad = lane >> 4, l16 = lane & 15;

    const int am0 = bm + wm + l16, am1 = am0 + 16;
    const bf16* a00 = s0 + (size_t)am0 * ld0 + quad * 8;
    const bf16* a01 = s0 + (size_t)am1 * ld0 + quad * 8;
    const bf16* a10 = s1 + (size_t)am0 * ld1 + quad * 8;
    const bf16* a11 = s1 + (size_t)am1 * ld1 + quad * 8;
    const bf16* a20 = s2 + (size_t)am0 * ld2 + quad * 8;
    const bf16* a21 = s2 + (size_t)am1 * ld2 + quad * 8;
    const bf16* b0p = BT + (size_t)(bn + wn + l16) * E2 + quad * 8;
    const bf16* b1p = BT + (size_t)(bn + wn + 16 + l16) * E2 + quad * 8;

    auto aload = [&](int k0, short8& f0, short8& f1) {
        if (k0 < E0) {
            f0 = *(const short8*)(a00 + k0);
            f1 = *(const short8*)(a01 + k0);
        } else if (k0 < E1) {
            f0 = *(const short8*)(a10 + (k0 - E0));
            f1 = *(const short8*)(a11 + (k0 - E0));
        } else {
            f0 = *(const short8*)(a20 + (k0 - E1));
            f1 = *(const short8*)(a21 + (k0 - E1));
        }
    };

    short8 A0[4], A1[4], Bw0[4], Bw1[4];
#pragma unroll
    for (int d = 0; d < 4; ++d) {                 // prologue: slices 0..3
        aload(d * 32, A0[d], A1[d]);
        Bw0[d] = *(const short8*)(b0p + d * 32);
        Bw1[d] = *(const short8*)(b1p + d * 32);
    }

    floatx4 acc[2][2] = {};

    constexpr int NS = E2 / 32;
#pragma unroll
    for (int s = 0; s < NS; ++s) {
        const int d = s & 3;
        acc[0][0] = __builtin_amdgcn_mfma_f32_16x16x32_bf16(A0[d], Bw0[d], acc[0][0], 0, 0, 0);
        acc[0][1] = __builtin_amdgcn_mfma_f32_16x16x32_bf16(A0[d], Bw1[d], acc[0][1], 0, 0, 0);
        acc[1][0] = __builtin_amdgcn_mfma_f32_16x16x32_bf16(A1[d], Bw0[d], acc[1][0], 0, 0, 0);
        acc[1][1] = __builtin_amdgcn_mfma_f32_16x16x32_bf16(A1[d], Bw1[d], acc[1][1], 0, 0, 0);
        const int kn = (s + 4) * 32;
        if (kn < E2) {                            // compile-time condition
            aload(kn, A0[d], A1[d]);
            Bw0[d] = *(const short8*)(b0p + kn);
            Bw1[d] = *(const short8*)(b1p + kn);
        }
    }

    // ---- epilogue (R2-verified layout) ----
#pragma unroll
    for (int tm = 0; tm < 2; ++tm)
#pragma unroll
        for (int tn = 0; tn < 2; ++tn) {
            const int col = bn + wn + tn * 16 + l16;
#pragma unroll
            for (int r = 0; r < 4; ++r) {
                const int row = bm + wm + tm * 16 + quad * 4 + r;
                float vv = acc[tm][tn][r] + bias[col];
                if (MODE == MG) {
                    float sg = 1.f / (1.f + __expf(-vv));
                    if (col < out) {
                        size_t idx = (size_t)row * out + col;
                        rh[idx] = f2bf(sg * hf[idx]);
                    } else {
                        zb[(size_t)row * out + (col - out)] = sg;
                    }
                } else if (MODE == MC) {
                    float c = tanhf(vv);
                    size_t idx = (size_t)row * out + col;
                    float zv = zb[idx], ho = hf[idx];
                    float hn = (t < lens[row]) ? (zv * ho + (1.f - zv) * c) : ho;
                    hf[idx] = hn;
                    hbo[idx] = f2bf(hn);
                } else {
                    y[(size_t)row * 512 + col] = tanhf(vv);
                }
            }
        }
}

// ---- wavefront sub-phase bodies (shared by coop kernel and fallback) ----
__device__ void do_gates(const Params& p, int ph)
{
    const int bid = blockIdx.x;
    int gl = -1, q = 0;
    if (bid < 64)       { gl = 0; q = bid; }
    else if (bid < 192) { gl = 1; q = bid - 64; }
    else if (bid < 448) { gl = 2; q = bid - 192; }
    if (gl < 0) return;
    const int t = ph - gl;
    if (t < 0 || t >= T_) return;
    const int bm = (q & 3) * 64, bn = (q >> 2) * 64;
    const bf16* hp = p.hb[gl][(t - 1) & 1];
    if (gl == 0) {
        const bf16* x = p.emb + (size_t)t * B_ * 32;
        phase_gemm<32, 544, 544, MG>(x, 32, hp, 512, hp, 512,
            p.kgT[0], p.gb[0], 512, p.hf[0], nullptr, p.rh[0], p.zb[0],
            nullptr, t, nullptr, bm, bn);
    } else if (gl == 1) {
        const bf16* x = p.hb[0][t & 1];
        phase_gemm<512, 1536, 1536, MG>(x, 512, hp, 1024, hp, 1024,
            p.kgT[1], p.gb[1], 1024, p.hf[1], nullptr, p.rh[1], p.zb[1],
            nullptr, t, nullptr, bm, bn);
    } else {
        const bf16* x = p.hb[1][t & 1];
        phase_gemm<1024, 3072, 3072, MG>(x, 1024, hp, 2048, hp, 2048,
            p.kgT[2], p.gb[2], 2048, p.hf[2], nullptr, p.rh[2], p.zb[2],
            nullptr, t, nullptr, bm, bn);
    }
}

__device__ void do_cand(const Params& p, int ph)
{
    const int bid = blockIdx.x;
    int cl = -1, q = 0;
    if (bid < 32)       { cl = 0; q = bid; }
    else if (bid < 96)  { cl = 1; q = bid - 32; }
    else if (bid < 224) { cl = 2; q = bid - 96; }
    if (cl < 0) return;
    const int t = ph - cl;
    if (t < 0 || t >= T_) return;
    const int bm = (q & 3) * 64, bn = (q >> 2) * 64;
    if (cl == 0) {
        const bf16* x = p.emb + (size_t)t * B_ * 32;
        phase_gemm<32, 544, 544, MC>(x, 32, p.rh[0], 512, p.rh[0], 512,
            p.kcT[0], p.cb[0], 512, p.hf[0], p.hb[0][t & 1], nullptr, p.zb[0],
            p.lens, t, nullptr, bm, bn);
    } else if (cl == 1) {
        const bf16* x = p.hb[0][t & 1];
        phase_gemm<512, 1536, 1536, MC>(x, 512, p.rh[1], 1024, p.rh[1], 1024,
            p.kcT[1], p.cb[1], 1024, p.hf[1], p.hb[1][t & 1], nullptr, p.zb[1],
            p.lens, t, nullptr, bm, bn);
    } else {
        const bf16* x = p.hb[1][t & 1];
        phase_gemm<1024, 3072, 3072, MC>(x, 1024, p.rh[2], 2048, p.rh[2], 2048,
            p.kcT[2], p.cb[2], 2048, p.hf[2], p.hb[2][t & 1], nullptr, p.zb[2],
            p.lens, t, nullptr, bm, bn);
    }
}

__device__ void do_dense(const Params& p)
{
    const int bid = blockIdx.x;
    if (bid >= 32) return;
    phase_gemm<512, 1536, 3584, MD>(
        p.hb[0][1], 512, p.hb[1][1], 1024, p.hb[2][1], 2048,
        p.dwT, p.db, 512, nullptr, nullptr, nullptr, nullptr,
        nullptr, 0, p.y, (bid & 3) * 64, (bid >> 2) * 64);
}

// ---- cooperative persistent kernel ----
__global__ __launch_bounds__(256, 2) void gru_k(Params p)
{
    int bc = 0;
    for (int ph = 0; ph < T_ + 2; ++ph) {
        do_gates(p, ph);
        phase_barrier(p.ctr + (size_t)bc * 32); ++bc;
        do_cand(p, ph);
        phase_barrier(p.ctr + (size_t)bc * 32); ++bc;
    }
    do_dense(p);
}

// ---- fallback: one launch per sub-phase (kernel boundary = sync) ----
__global__ __launch_bounds__(256, 2) void gru_phase_k(Params p, int ph, int sub)
{
    if (sub == 0) do_gates(p, ph);
    else          do_cand(p, ph);
}
__global__ __launch_bounds__(256, 2) void gru_dense_k(Params p)
{
    do_dense(p);
}

extern "C" void kernel_launch(void* const* d_in, const int* in_sizes, int n_in,
                              void* d_out, int out_size, void* d_ws, size_t ws_size,
                              hipStream_t stream)
{
    const int*   seq  = (const int*)d_in[0];
    const int*   lens = (const int*)d_in[1];
    const float* tab  = (const float*)d_in[2];
    const float* gkF[3] = {(const float*)d_in[3], (const float*)d_in[7], (const float*)d_in[11]};
    const float* gbF[3] = {(const float*)d_in[4], (const float*)d_in[8], (const float*)d_in[12]};
    const float* ckF[3] = {(const float*)d_in[5], (const float*)d_in[9], (const float*)d_in[13]};
    const float* cbF[3] = {(const float*)d_in[6], (const float*)d_in[10], (const float*)d_in[14]};
    const float* dwF = (const float*)d_in[15];
    const float* dbF = (const float*)d_in[16];

    const int outs[3] = {512, 1024, 2048};
    const int ins[3]  = {32, 512, 1024};

    char* w = (char*)d_ws;
    auto alloc = [&](size_t bytes) -> void* {
        void* pp = (void*)w;
        w += (bytes + 255) & ~(size_t)255;
        return pp;
    };

    Params p;
    p.lens = lens;
    p.db   = dbF;
    p.y    = (float*)d_out;

    bf16* kgT[3]; bf16* kcT[3];
    for (int l = 0; l < 3; ++l) {
        const int Kt = ins[l] + outs[l];
        kgT[l] = (bf16*)alloc((size_t)2 * outs[l] * Kt * sizeof(bf16));
        kcT[l] = (bf16*)alloc((size_t)outs[l] * Kt * sizeof(bf16));
        p.kgT[l] = kgT[l];
        p.kcT[l] = kcT[l];
        p.gb[l] = gbF[l];
        p.cb[l] = cbF[l];
    }
    bf16* dwT = (bf16*)alloc((size_t)512 * 3584 * sizeof(bf16));
    p.dwT = dwT;

    bf16* emb_all = (bf16*)alloc((size_t)T_ * B_ * 32 * sizeof(bf16));
    p.emb = emb_all;

    for (int l = 0; l < 3; ++l) {
        p.hf[l] = (float*)alloc((size_t)B_ * outs[l] * sizeof(float));
        bf16* hbbuf = (bf16*)alloc((size_t)2 * B_ * outs[l] * sizeof(bf16));
        p.hb[l][0] = hbbuf;
        p.hb[l][1] = hbbuf + (size_t)B_ * outs[l];
        p.rh[l] = (bf16*)alloc((size_t)B_ * outs[l] * sizeof(bf16));
        p.zb[l] = (float*)alloc((size_t)B_ * outs[l] * sizeof(float));
    }

    const int NBAR = 2 * (T_ + 2);
    unsigned* ctr = (unsigned*)alloc((size_t)NBAR * 32 * sizeof(unsigned));
    p.ctr = ctr;

    // weight transposes (fp32 -> bf16 [N][K])
    for (int l = 0; l < 3; ++l) {
        const int Kt = ins[l] + outs[l];
        tpose_k<<<dim3(Kt / 32, 2 * outs[l] / 32), 256, 0, stream>>>(gkF[l], kgT[l], Kt, 2 * outs[l]);
        tpose_k<<<dim3(Kt / 32, outs[l] / 32), 256, 0, stream>>>(ckF[l], kcT[l], Kt, outs[l]);
    }
    tpose_k<<<dim3(3584 / 32, 512 / 32), 256, 0, stream>>>(dwF, dwT, 3584, 512);

    // zero h state (both parities) + barrier counters
    for (int l = 0; l < 3; ++l) {
        hipMemsetAsync(p.hf[l], 0, (size_t)B_ * outs[l] * sizeof(float), stream);
        hipMemsetAsync(p.hb[l][0], 0, (size_t)2 * B_ * outs[l] * sizeof(bf16), stream);
    }
    hipMemsetAsync(ctr, 0, (size_t)NBAR * 32 * sizeof(unsigned), stream);

    embed_k<<<T_ * B_ * 4 / 256, 256, 0, stream>>>(seq, tab, emb_all);

    void* args[] = {&p};
    hipError_t err = hipLaunchCooperativeKernel(reinterpret_cast<void*>(gru_k),
                                                dim3(GRID), dim3(256), args, 0, stream);
    if (err != hipSuccess) {
        (void)hipGetLastError();   // clear error state
        for (int ph = 0; ph < T_ + 2; ++ph) {
            gru_phase_k<<<GRID, 256, 0, stream>>>(p, ph, 0);
            gru_phase_k<<<GRID, 256, 0, stream>>>(p, ph, 1);
        }
        gru_dense_k<<<GRID, 256, 0, stream>>>(p);
    }
}

// Round 7
// 42890.775 us; speedup vs baseline: 2.2154x; 1.1287x over previous
//
#include <hip/hip_runtime.h>
#include <hip/hip_bf16.h>

using bf16 = __hip_bfloat16;
typedef __attribute__((ext_vector_type(8))) short short8;
typedef __attribute__((ext_vector_type(4))) float floatx4;

static constexpr int B_ = 256;   // batch
static constexpr int T_ = 128;   // time steps
static constexpr int GRID = 512; // 2 blocks/CU, cooperative

__device__ __forceinline__ bf16 f2bf(float v) { return __float2bfloat16(v); }

enum { MG = 0, MC = 1, MD = 2 };

struct Params {
    const bf16* emb;          // [T][B][32]
    const int*  lens;
    const bf16* kgT[3];       // [2*out][KtPad] transposed bf16
    const bf16* kcT[3];       // [out][KtPad]
    const float* gb[3];
    const float* cb[3];
    float* hf[3];             // fp32 running h
    bf16*  hb[3][2];          // bf16 h, double-buffered by t parity
    bf16*  rh[3];             // bf16 r*h
    float* zb[3];             // fp32 z
    const bf16* dwT;          // [512][3584]
    const float* db;
    float* y;                 // [256][512] fp32
    const bf16* zbuf;         // 256 zeros (L0 K-pad reads)
    unsigned* ctr;            // one-shot counters, stride 32 uints per barrier
};

// R4/R6-proven one-shot grid barrier (device-scope atomics + fences)
__device__ __forceinline__ void phase_barrier(unsigned* c)
{
    __syncthreads();
    __threadfence();
    if (threadIdx.x == 0) {
        atomicAdd(c, 1u);
        while (__hip_atomic_load(c, __ATOMIC_RELAXED, __HIP_MEMORY_SCOPE_AGENT) < (unsigned)GRID)
            __builtin_amdgcn_s_sleep(1);
    }
    __syncthreads();
    __threadfence();
}

// ---- fp32 [K][N] -> bf16 [N][K] tiled transpose (dst leading dim ldD) ----
__global__ __launch_bounds__(256) void tpose_k(const float* __restrict__ src,
                                               bf16* __restrict__ dst,
                                               int K, int N, int ldD)
{
    __shared__ float tile[32][33];
    const int kb = blockIdx.x * 32, nb = blockIdx.y * 32;
    const int tx = threadIdx.x & 31, ty = threadIdx.x >> 5;
    for (int i = ty; i < 32; i += 8)
        tile[i][tx] = src[(size_t)(kb + i) * N + nb + tx];
    __syncthreads();
    for (int i = ty; i < 32; i += 8)
        dst[(size_t)(nb + i) * ldD + kb + tx] = f2bf(tile[tx][i]);
}

// ---- emb_all[t][b][0:32] = bf16(emb_table[seq[b][t]]) ----
__global__ __launch_bounds__(256) void embed_k(const int* __restrict__ seq,
                                               const float* __restrict__ tab,
                                               bf16* __restrict__ emb_all)
{
    int c = blockIdx.x * 256 + threadIdx.x;
    int t = c >> 10;
    int r = c & 1023;
    int b = r >> 2, i = r & 3;
    int tok = seq[b * T_ + t];
    const float* s = tab + (size_t)tok * 32 + i * 8;
    bf16 tmp[8];
#pragma unroll
    for (int j = 0; j < 8; ++j) tmp[j] = f2bf(s[j]);
    *(uint4*)(emb_all + ((size_t)t * B_ + b) * 32 + i * 8) = *(uint4*)tmp;
}

// ---- zero 256 bf16 ----
__global__ void zeroz_k(bf16* z) { z[threadIdx.x] = f2bf(0.f); }

// One 64x64 tile, no LDS. A = [s0|s1|s2] row-major bf16, segment ends
// E0<=E1<=E2 (compile-time, multiples of 32; E2 = padded K = NS*32, NS%4==0).
// BT = bf16 [N][E2]. 4 waves of 32x32 via 16x16x32 mfma.
// Rolled K-loop, explicit depth-4 register rotation: steady ~12-16
// outstanding global loads per wave, 1:1 MFMA:load interleave.
template <int E0, int E1, int E2, int MODE>
__device__ void phase_gemm(
    const bf16* __restrict__ s0, int ld0,
    const bf16* __restrict__ s1, int ld1,
    const bf16* __restrict__ s2, int ld2,
    const bf16* __restrict__ BT,
    const float* __restrict__ bias, int out,
    float* __restrict__ hf, bf16* __restrict__ hbo,
    bf16* __restrict__ rh, float* __restrict__ zb,
    const int* __restrict__ lens, int t, float* __restrict__ y,
    int bm, int bn)
{
    const int tid  = threadIdx.x;
    const int lane = tid & 63, wv = tid >> 6;
    const int wm   = (wv >> 1) * 32, wn = (wv & 1) * 32;
    const int quad = lane >> 4, l16 = lane & 15;

    const int am0 = bm + wm + l16, am1 = am0 + 16;
    const bf16* a00 = s0 + (size_t)am0 * ld0 + quad * 8;
    const bf16* a01 = s0 + (size_t)am1 * ld0 + quad * 8;
    const bf16* a10 = s1 + (size_t)am0 * ld1 + quad * 8;
    const bf16* a11 = s1 + (size_t)am1 * ld1 + quad * 8;
    const bf16* a20 = s2 + (size_t)am0 * ld2 + quad * 8;
    const bf16* a21 = s2 + (size_t)am1 * ld2 + quad * 8;
    const bf16* b0p = BT + (size_t)(bn + wn + l16) * E2 + quad * 8;
    const bf16* b1p = BT + (size_t)(bn + wn + 16 + l16) * E2 + quad * 8;

    auto aload = [&](int k0, short8& f0, short8& f1) {
        if (k0 < E0) {
            f0 = *(const short8*)(a00 + k0);
            f1 = *(const short8*)(a01 + k0);
        } else if (E1 == E2 || k0 < E1) {
            f0 = *(const short8*)(a10 + (k0 - E0));
            f1 = *(const short8*)(a11 + (k0 - E0));
        } else {
            f0 = *(const short8*)(a20 + (k0 - E1));
            f1 = *(const short8*)(a21 + (k0 - E1));
        }
    };

    short8 fA0[4], fA1[4], fB0[4], fB1[4];
#pragma unroll
    for (int d = 0; d < 4; ++d) {
        aload(d * 32, fA0[d], fA1[d]);
        fB0[d] = *(const short8*)(b0p + d * 32);
        fB1[d] = *(const short8*)(b1p + d * 32);
    }

    floatx4 acc00 = {0,0,0,0}, acc01 = {0,0,0,0};
    floatx4 acc10 = {0,0,0,0}, acc11 = {0,0,0,0};

    constexpr int NS = E2 / 32;
    static_assert(NS % 4 == 0 && NS >= 8, "NS must be multiple of 4");

#define GSTEP(j, LD)                                                              \
    do {                                                                          \
        acc00 = __builtin_amdgcn_mfma_f32_16x16x32_bf16(fA0[j], fB0[j], acc00, 0, 0, 0); \
        acc01 = __builtin_amdgcn_mfma_f32_16x16x32_bf16(fA0[j], fB1[j], acc01, 0, 0, 0); \
        acc10 = __builtin_amdgcn_mfma_f32_16x16x32_bf16(fA1[j], fB0[j], acc10, 0, 0, 0); \
        acc11 = __builtin_amdgcn_mfma_f32_16x16x32_bf16(fA1[j], fB1[j], acc11, 0, 0, 0); \
        if (LD) {                                                                 \
            const int kn = k0 + (j + 4) * 32;                                     \
            aload(kn, fA0[j], fA1[j]);                                            \
            fB0[j] = *(const short8*)(b0p + kn);                                  \
            fB1[j] = *(const short8*)(b1p + kn);                                  \
        }                                                                         \
    } while (0)

    for (int s = 0; s < NS - 4; s += 4) {
        const int k0 = s * 32;
        GSTEP(0, true); GSTEP(1, true); GSTEP(2, true); GSTEP(3, true);
    }
    {
        const int k0 = 0; (void)k0;
        GSTEP(0, false); GSTEP(1, false); GSTEP(2, false); GSTEP(3, false);
    }
#undef GSTEP

    floatx4 accs[2][2] = {{acc00, acc01}, {acc10, acc11}};

    // ---- epilogue (R2-verified layout) ----
#pragma unroll
    for (int tm = 0; tm < 2; ++tm)
#pragma unroll
        for (int tn = 0; tn < 2; ++tn) {
            const int col = bn + wn + tn * 16 + l16;
#pragma unroll
            for (int r = 0; r < 4; ++r) {
                const int row = bm + wm + tm * 16 + quad * 4 + r;
                float vv = accs[tm][tn][r] + bias[col];
                if (MODE == MG) {
                    float sg = 1.f / (1.f + __expf(-vv));
                    if (col < out) {
                        size_t idx = (size_t)row * out + col;
                        rh[idx] = f2bf(sg * hf[idx]);
                    } else {
                        zb[(size_t)row * out + (col - out)] = sg;
                    }
                } else if (MODE == MC) {
                    float c = tanhf(vv);
                    size_t idx = (size_t)row * out + col;
                    float zv = zb[idx], ho = hf[idx];
                    float hn = (t < lens[row]) ? (zv * ho + (1.f - zv) * c) : ho;
                    hf[idx] = hn;
                    hbo[idx] = f2bf(hn);
                } else {
                    y[(size_t)row * 512 + col] = tanhf(vv);
                }
            }
        }
}

// ---- wavefront sub-phase bodies; XCD-pinned tile ownership ----
// xcd = bid & 7 (dispatch heuristic, perf-only); j = bid >> 3 in [0,64)
__device__ void do_gates(const Params& p, int ph)
{
    const int xcd = blockIdx.x & 7, j = blockIdx.x >> 3;
    int gl, local, npx;
    if (j < 8)       { gl = 0; local = j;      npx = 2; }   // L0: N=1024, 16 ntiles
    else if (j < 24) { gl = 1; local = j - 8;  npx = 4; }   // L1: N=2048, 32 ntiles
    else if (j < 56) { gl = 2; local = j - 24; npx = 8; }   // L2: N=4096, 64 ntiles
    else return;
    const int t = ph - gl;
    if (t < 0 || t >= T_) return;
    const int bm = (local & 3) * 64;
    const int bn = (xcd * npx + (local >> 2)) * 64;
    const bf16* hp = p.hb[gl][(t - 1) & 1];
    if (gl == 0) {
        const bf16* x = p.emb + (size_t)t * B_ * 32;
        phase_gemm<32, 544, 640, MG>(x, 32, hp, 512, p.zbuf, 0,
            p.kgT[0], p.gb[0], 512, p.hf[0], nullptr, p.rh[0], p.zb[0],
            nullptr, t, nullptr, bm, bn);
    } else if (gl == 1) {
        const bf16* x = p.hb[0][t & 1];
        phase_gemm<512, 1536, 1536, MG>(x, 512, hp, 1024, p.zbuf, 0,
            p.kgT[1], p.gb[1], 1024, p.hf[1], nullptr, p.rh[1], p.zb[1],
            nullptr, t, nullptr, bm, bn);
    } else {
        const bf16* x = p.hb[1][t & 1];
        phase_gemm<1024, 3072, 3072, MG>(x, 1024, hp, 2048, p.zbuf, 0,
            p.kgT[2], p.gb[2], 2048, p.hf[2], nullptr, p.rh[2], p.zb[2],
            nullptr, t, nullptr, bm, bn);
    }
}

__device__ void do_cand(const Params& p, int ph)
{
    const int xcd = blockIdx.x & 7, j = blockIdx.x >> 3;
    int cl, local, npx;
    if (j < 4)       { cl = 0; local = j;      npx = 1; }   // L0: N=512, 8 ntiles
    else if (j < 12) { cl = 1; local = j - 4;  npx = 2; }   // L1: N=1024, 16
    else if (j < 28) { cl = 2; local = j - 12; npx = 4; }   // L2: N=2048, 32
    else return;
    const int t = ph - cl;
    if (t < 0 || t >= T_) return;
    const int bm = (local & 3) * 64;
    const int bn = (xcd * npx + (local >> 2)) * 64;
    if (cl == 0) {
        const bf16* x = p.emb + (size_t)t * B_ * 32;
        phase_gemm<32, 544, 640, MC>(x, 32, p.rh[0], 512, p.zbuf, 0,
            p.kcT[0], p.cb[0], 512, p.hf[0], p.hb[0][t & 1], nullptr, p.zb[0],
            p.lens, t, nullptr, bm, bn);
    } else if (cl == 1) {
        const bf16* x = p.hb[0][t & 1];
        phase_gemm<512, 1536, 1536, MC>(x, 512, p.rh[1], 1024, p.zbuf, 0,
            p.kcT[1], p.cb[1], 1024, p.hf[1], p.hb[1][t & 1], nullptr, p.zb[1],
            p.lens, t, nullptr, bm, bn);
    } else {
        const bf16* x = p.hb[1][t & 1];
        phase_gemm<1024, 3072, 3072, MC>(x, 1024, p.rh[2], 2048, p.zbuf, 0,
            p.kcT[2], p.cb[2], 2048, p.hf[2], p.hb[2][t & 1], nullptr, p.zb[2],
            p.lens, t, nullptr, bm, bn);
    }
}

__device__ void do_dense(const Params& p)
{
    const int xcd = blockIdx.x & 7, j = blockIdx.x >> 3;
    if (j >= 4) return;
    phase_gemm<512, 1536, 3584, MD>(
        p.hb[0][1], 512, p.hb[1][1], 1024, p.hb[2][1], 2048,
        p.dwT, p.db, 512, nullptr, nullptr, nullptr, nullptr,
        nullptr, 0, p.y, (j & 3) * 64, xcd * 64);
}

// ---- cooperative persistent kernel ----
__global__ __launch_bounds__(256, 2) void gru_k(Params p)
{
    int bc = 0;
    for (int ph = 0; ph < T_ + 2; ++ph) {
        do_gates(p, ph);
        phase_barrier(p.ctr + (size_t)bc * 32); ++bc;
        do_cand(p, ph);
        phase_barrier(p.ctr + (size_t)bc * 32); ++bc;
    }
    do_dense(p);
}

// ---- fallback: one launch per sub-phase (kernel boundary = sync) ----
__global__ __launch_bounds__(256, 2) void gru_phase_k(Params p, int ph, int sub)
{
    if (sub == 0) do_gates(p, ph);
    else          do_cand(p, ph);
}
__global__ __launch_bounds__(256, 2) void gru_dense_k(Params p)
{
    do_dense(p);
}

extern "C" void kernel_launch(void* const* d_in, const int* in_sizes, int n_in,
                              void* d_out, int out_size, void* d_ws, size_t ws_size,
                              hipStream_t stream)
{
    const int*   seq  = (const int*)d_in[0];
    const int*   lens = (const int*)d_in[1];
    const float* tab  = (const float*)d_in[2];
    const float* gkF[3] = {(const float*)d_in[3], (const float*)d_in[7], (const float*)d_in[11]};
    const float* gbF[3] = {(const float*)d_in[4], (const float*)d_in[8], (const float*)d_in[12]};
    const float* ckF[3] = {(const float*)d_in[5], (const float*)d_in[9], (const float*)d_in[13]};
    const float* cbF[3] = {(const float*)d_in[6], (const float*)d_in[10], (const float*)d_in[14]};
    const float* dwF = (const float*)d_in[15];
    const float* dbF = (const float*)d_in[16];

    const int outs[3] = {512, 1024, 2048};
    const int ins[3]  = {32, 512, 1024};
    const int ldp[3]  = {640, 1536, 3072};   // padded K (row length of transposed W)

    char* w = (char*)d_ws;
    auto alloc = [&](size_t bytes) -> void* {
        void* pp = (void*)w;
        w += (bytes + 255) & ~(size_t)255;
        return pp;
    };

    Params p;
    p.lens = lens;
    p.db   = dbF;
    p.y    = (float*)d_out;

    bf16* kgT[3]; bf16* kcT[3];
    for (int l = 0; l < 3; ++l) {
        kgT[l] = (bf16*)alloc((size_t)2 * outs[l] * ldp[l] * sizeof(bf16));
        kcT[l] = (bf16*)alloc((size_t)outs[l] * ldp[l] * sizeof(bf16));
        p.kgT[l] = kgT[l];
        p.kcT[l] = kcT[l];
        p.gb[l] = gbF[l];
        p.cb[l] = cbF[l];
    }
    bf16* dwT = (bf16*)alloc((size_t)512 * 3584 * sizeof(bf16));
    p.dwT = dwT;

    bf16* emb_all = (bf16*)alloc((size_t)T_ * B_ * 32 * sizeof(bf16));
    p.emb = emb_all;

    for (int l = 0; l < 3; ++l) {
        p.hf[l] = (float*)alloc((size_t)B_ * outs[l] * sizeof(float));
        bf16* hbbuf = (bf16*)alloc((size_t)2 * B_ * outs[l] * sizeof(bf16));
        p.hb[l][0] = hbbuf;
        p.hb[l][1] = hbbuf + (size_t)B_ * outs[l];
        p.rh[l] = (bf16*)alloc((size_t)B_ * outs[l] * sizeof(bf16));
        p.zb[l] = (float*)alloc((size_t)B_ * outs[l] * sizeof(float));
    }
    bf16* zbuf = (bf16*)alloc(256 * sizeof(bf16));
    p.zbuf = zbuf;

    const int NBAR = 2 * (T_ + 2);
    unsigned* ctr = (unsigned*)alloc((size_t)NBAR * 32 * sizeof(unsigned));
    p.ctr = ctr;

    // weight transposes (fp32 -> bf16 [N][ldp]); L0 pad cols stay ws-poison
    // (finite as bf16) and are multiplied by A-side zeros from zbuf.
    for (int l = 0; l < 3; ++l) {
        const int Kt = ins[l] + outs[l];
        tpose_k<<<dim3(Kt / 32, 2 * outs[l] / 32), 256, 0, stream>>>(gkF[l], kgT[l], Kt, 2 * outs[l], ldp[l]);
        tpose_k<<<dim3(Kt / 32, outs[l] / 32), 256, 0, stream>>>(ckF[l], kcT[l], Kt, outs[l], ldp[l]);
    }
    tpose_k<<<dim3(3584 / 32, 512 / 32), 256, 0, stream>>>(dwF, dwT, 3584, 512, 3584);

    // zero h state (both parities) + pad-read buffer + barrier counters
    for (int l = 0; l < 3; ++l) {
        hipMemsetAsync(p.hf[l], 0, (size_t)B_ * outs[l] * sizeof(float), stream);
        hipMemsetAsync(p.hb[l][0], 0, (size_t)2 * B_ * outs[l] * sizeof(bf16), stream);
    }
    zeroz_k<<<1, 256, 0, stream>>>(zbuf);
    hipMemsetAsync(ctr, 0, (size_t)NBAR * 32 * sizeof(unsigned), stream);

    embed_k<<<T_ * B_ * 4 / 256, 256, 0, stream>>>(seq, tab, emb_all);

    void* args[] = {&p};
    hipError_t err = hipLaunchCooperativeKernel(reinterpret_cast<void*>(gru_k),
                                                dim3(GRID), dim3(256), args, 0, stream);
    if (err != hipSuccess) {
        (void)hipGetLastError();   // clear error state
        for (int ph = 0; ph < T_ + 2; ++ph) {
            gru_phase_k<<<GRID, 256, 0, stream>>>(p, ph, 0);
            gru_phase_k<<<GRID, 256, 0, stream>>>(p, ph, 1);
        }
        gru_dense_k<<<GRID, 256, 0, stream>>>(p);
    }
}